// Round 1
// baseline (212.831 us; speedup 1.0000x reference)
//
#include <hip/hip_runtime.h>
#include <math.h>

// Problem constants (B=16, S=2048, H=1024)
#define BATCH 16
#define SEQ   2048
#define HID   1024

// ---------------------------------------------------------------------------
// Kernel A: partial mat-vec  partial[chunk][j] = sum_{h in chunk} v[h]*W[h,1024+j]
// attn_w is [H, 2H] row-major; we only need columns [H, 2H) (the encoder half;
// the hidden half feeds a per-row constant that cancels in softmax).
// grid = 128 blocks (8 rows each), block = 256 threads * float4 = 1024 cols.
// ---------------------------------------------------------------------------
__global__ __launch_bounds__(256) void we_partial_kernel(
    const float* __restrict__ attn_w,
    const float* __restrict__ v,
    float* __restrict__ partial)
{
    const int tid   = threadIdx.x;     // 0..255
    const int chunk = blockIdx.x;      // 0..127
    const int h0    = chunk * 8;

    float4 acc = make_float4(0.f, 0.f, 0.f, 0.f);
#pragma unroll
    for (int r = 0; r < 8; ++r) {
        const int h = h0 + r;
        const float vh = v[h];
        const float4 a =
            ((const float4*)(attn_w + (size_t)h * (2 * HID) + HID))[tid];
        acc.x += vh * a.x;
        acc.y += vh * a.y;
        acc.z += vh * a.z;
        acc.w += vh * a.w;
    }
    ((float4*)(partial + (size_t)chunk * HID))[tid] = acc;
}

// ---------------------------------------------------------------------------
// Kernel B: w2[j] = sum_{chunk<128} partial[chunk][j].  grid=4, block=256.
// 512 KB, L2-hot.
// ---------------------------------------------------------------------------
__global__ __launch_bounds__(256) void we_reduce_kernel(
    const float* __restrict__ partial,
    float* __restrict__ w2)
{
    const int j = blockIdx.x * 256 + threadIdx.x;  // 0..1023
    float acc = 0.f;
#pragma unroll 8
    for (int y = 0; y < 128; ++y)
        acc += partial[(size_t)y * HID + j];
    w2[j] = acc;
}

// ---------------------------------------------------------------------------
// Kernel C (dominant): scores[row] = enc[row,:] . w2   for row in [0, B*S).
// One wave per 4 rows; lane l covers elements {c*256 + l*4 .. +3 | c<4}.
// w2 fragment (16 floats) preloaded into VGPRs, amortized over 4 rows.
// grid = 2048 blocks * 256 thr = 8192 waves = 32 waves/CU (full occupancy).
// 134 MB encoder read -> HBM-bound.
// ---------------------------------------------------------------------------
__global__ __launch_bounds__(256) void scores_kernel(
    const float* __restrict__ enc,
    const float* __restrict__ w2,
    float* __restrict__ scores)
{
    const int wave = (int)((blockIdx.x * 256 + threadIdx.x) >> 6); // 0..8191
    const int lane = threadIdx.x & 63;

    float4 w[4];
#pragma unroll
    for (int c = 0; c < 4; ++c)
        w[c] = ((const float4*)w2)[c * 64 + lane];

#pragma unroll
    for (int i = 0; i < 4; ++i) {
        const int row = wave * 4 + i;  // 0..32767
        const float4* rp = (const float4*)(enc + (size_t)row * HID);
        float acc = 0.f;
#pragma unroll
        for (int c = 0; c < 4; ++c) {
            const float4 e = rp[c * 64 + lane];
            acc += e.x * w[c].x + e.y * w[c].y + e.z * w[c].z + e.w * w[c].w;
        }
        // wave64 shuffle reduction
#pragma unroll
        for (int off = 32; off > 0; off >>= 1)
            acc += __shfl_down(acc, off, 64);
        if (lane == 0)
            scores[row] = acc;
    }
}

// ---------------------------------------------------------------------------
// Kernel D: row softmax over [BATCH, SEQ].  One block per batch row.
// ---------------------------------------------------------------------------
__global__ __launch_bounds__(256) void softmax_kernel(
    const float* __restrict__ scores,
    float* __restrict__ out)
{
    const int b   = blockIdx.x;
    const int tid = threadIdx.x;
    const float* s = scores + (size_t)b * SEQ;

    __shared__ float red[256];

    float local[8];
    float m = -INFINITY;
#pragma unroll
    for (int i = 0; i < 8; ++i) {
        local[i] = s[tid + i * 256];
        m = fmaxf(m, local[i]);
    }
    red[tid] = m;
    __syncthreads();
    for (int st = 128; st > 0; st >>= 1) {
        if (tid < st) red[tid] = fmaxf(red[tid], red[tid + st]);
        __syncthreads();
    }
    m = red[0];
    __syncthreads();

    float e[8];
    float sum = 0.f;
#pragma unroll
    for (int i = 0; i < 8; ++i) {
        e[i] = __expf(local[i] - m);
        sum += e[i];
    }
    red[tid] = sum;
    __syncthreads();
    for (int st = 128; st > 0; st >>= 1) {
        if (tid < st) red[tid] += red[tid + st];
        __syncthreads();
    }
    const float inv = 1.f / red[0];
#pragma unroll
    for (int i = 0; i < 8; ++i)
        out[(size_t)b * SEQ + tid + i * 256] = e[i] * inv;
}

// ---------------------------------------------------------------------------
// Launch.  Inputs (fp32): hidden[16384], encoder_outputs[33554432],
// attn_w[2097152], attn_b[1024], v[1024].  Output: fp32 [16*2048].
// hidden & attn_b are provably unused (per-row constants cancel in softmax).
//
// ws layout (floats): [0,1024)=w2 | [1024,132096)=partials | [132096,164864)=scores
// total 644 KB.
// ---------------------------------------------------------------------------
extern "C" void kernel_launch(void* const* d_in, const int* in_sizes, int n_in,
                              void* d_out, int out_size, void* d_ws, size_t ws_size,
                              hipStream_t stream)
{
    const float* enc    = (const float*)d_in[1];
    const float* attn_w = (const float*)d_in[2];
    const float* v      = (const float*)d_in[4];

    float* ws      = (float*)d_ws;
    float* w2      = ws;
    float* partial = ws + HID;
    float* scores  = ws + HID + 128 * HID;

    we_partial_kernel<<<128, 256, 0, stream>>>(attn_w, v, partial);
    we_reduce_kernel <<<4,   256, 0, stream>>>(partial, w2);
    scores_kernel    <<<2048, 256, 0, stream>>>(enc, w2, scores);
    softmax_kernel   <<<BATCH, 256, 0, stream>>>(scores, (float*)d_out);
}